// Round 10
// baseline (113.625 us; speedup 1.0000x reference)
//
#include <hip/hip_runtime.h>
#include <hip/hip_fp16.h>

typedef __attribute__((ext_vector_type(8)))  _Float16 half8;
typedef __attribute__((ext_vector_type(16))) float    f32x16;

#define B_   16
#define NPTS 4096                      // points per batch (N == M == 4096)

constexpr int BLK  = 512;              // 8 waves = 4 query-groups x 2 target-parities
constexpr int QPB  = 256;              // queries per block (4 groups x 64)
constexpr int NQC  = NPTS / QPB;       // 16 query chunks
constexpr int RT   = 1024;             // targets staged per round (16 KB LDS)
constexpr int NR   = NPTS / RT;        // 4 rounds
constexpr int TPR  = RT / 32;          // 32 tiles of 32 targets per round
constexpr int NBLK = 2 * B_ * NQC;     // 512 blocks

__device__ __forceinline__ float min3f(float a, float b, float c) {
    return fminf(fminf(a, b), c);      // -> v_min3_f32
}

// Build the fp16 B-fragment [x,y,z,1,1,0,0,0] (both K-halves identical)
// for query pointer qp; also return |q|^2 of the fp16-rounded coords.
__device__ __forceinline__ half8 make_bfrag(const float* qp, float& q2) {
    __half hx = __float2half(qp[0]);
    __half hy = __float2half(qp[1]);
    __half hz = __float2half(qp[2]);
    float fx = __half2float(hx), fy = __half2float(hy), fz = __half2float(hz);
    q2 = fmaf(fx, fx, fmaf(fy, fy, fz * fz));
    uint4 bu;
    bu.x = (unsigned)__half_as_ushort(hx) | ((unsigned)__half_as_ushort(hy) << 16);
    bu.y = (unsigned)__half_as_ushort(hz) | (0x3C00u << 16);   // {z, 1.0}
    bu.z = 0x3C00u;                                            // {1.0, 0}
    bu.w = 0u;
    return __builtin_bit_cast(half8, bu);
}

// ------------------------------------------------------------------
// Fused MFMA chamfer, ILP-widened. Wave owns 64 queries (two B-frags);
// per 32-target tile: ONE broadcast ds_read_b128 feeds TWO independent
// mfma_f32_32x32x16_f16, whose results fold into two persistent
// 16-element running-min vectors (no per-tile tree, no AGPR readback
// chain on the critical path). Layout/numerics identical to R7-R9
// (absmax 0): A row = [-2x,-2y,-2z,g2hi,g2lo,0,0,0], D = 2(|g|^2-2q.g),
// d^2 = 0.5*minD + |q|^2 from the SAME fp16-rounded coords.
__global__ __launch_bounds__(BLK, 4) void chamfer_mfma(
        const float* __restrict__ pred, const float* __restrict__ gt,
        float* __restrict__ accum, unsigned* __restrict__ counter,
        float* __restrict__ out) {
    const int qc  = blockIdx.x;
    const int b   = blockIdx.y;
    const int dir = blockIdx.z;
    const float* qsrc = dir ? gt   : pred;   // queries
    const float* tsrc = dir ? pred : gt;     // targets

    __shared__ uint4 sh[RT];                 // 16 KB staged A-frag rows
    __shared__ float comb[2][QPB];           // cross-parity merge
    __shared__ float q2s[QPB];               // per-query |q|^2
    __shared__ float ps[4];

    const int tid  = threadIdx.x;
    const int lane = tid & 63;
    const int wv   = tid >> 6;
    const int m    = lane & 31;
    const int g    = wv & 3;                 // query group (64 queries)
    const int h    = wv >> 2;                // target parity

    // ---- two B fragments: queries g*64+m and g*64+32+m ----
    const float* qp0 = qsrc + (b * NPTS + qc * QPB + g * 64 + m) * 3;
    float q2a, q2b;
    const half8 bfrag0 = make_bfrag(qp0,          q2a);
    const half8 bfrag1 = make_bfrag(qp0 + 32 * 3, q2b);
    if (h == 0 && lane < 32) {
        q2s[g * 64 + m]      = q2a;
        q2s[g * 64 + 32 + m] = q2b;
    }

    f32x16 zero;
#pragma unroll
    for (int i = 0; i < 16; ++i) zero[i] = 0.0f;
    f32x16 mn0 = zero, mn1 = zero;
#pragma unroll
    for (int i = 0; i < 16; ++i) { mn0[i] = 1e30f; mn1[i] = 1e30f; }

    for (int r = 0; r < NR; ++r) {
        if (r) __syncthreads();
        // ---- stage RT targets as A-frag rows (2 per thread) ----
        const float* tp = tsrc + (b * NPTS + r * RT) * 3;
#pragma unroll
        for (int k = 0; k < RT / BLK; ++k) {
            int j = k * BLK + tid;
            __half hx = __float2half(tp[3 * j + 0]);
            __half hy = __float2half(tp[3 * j + 1]);
            __half hz = __float2half(tp[3 * j + 2]);
            float fx = __half2float(hx), fy = __half2float(hy), fz = __half2float(hz);
            float g2 = fmaf(fx, fx, fmaf(fy, fy, fz * fz));
            __half ax = __float2half(-2.0f * fx);
            __half ay = __float2half(-2.0f * fy);
            __half az = __float2half(-2.0f * fz);
            __half g2hi = __float2half(g2);
            __half g2lo = __float2half(g2 - __half2float(g2hi));
            uint4 w;
            w.x = (unsigned)__half_as_ushort(ax) | ((unsigned)__half_as_ushort(ay) << 16);
            w.y = (unsigned)__half_as_ushort(az) | ((unsigned)__half_as_ushort(g2hi) << 16);
            w.z = (unsigned)__half_as_ushort(g2lo);
            w.w = 0u;
            sh[j] = w;
        }
        __syncthreads();

        // ---- 16 tiles of this wave's parity: 1 ds_read -> 2 MFMAs ----
#pragma unroll 4
        for (int t = h; t < TPR; t += 2) {
            uint4 au = sh[t * 32 + m];       // lanes L, L+32 share addr
            half8 afrag = __builtin_bit_cast(half8, au);
            f32x16 d0 = __builtin_amdgcn_mfma_f32_32x32x16_f16(afrag, bfrag0, zero, 0, 0, 0);
            f32x16 d1 = __builtin_amdgcn_mfma_f32_32x32x16_f16(afrag, bfrag1, zero, 0, 0, 0);
#pragma unroll
            for (int i = 0; i < 16; ++i) mn0[i] = fminf(mn0[i], d0[i]);
#pragma unroll
            for (int i = 0; i < 16; ++i) mn1[i] = fminf(mn1[i], d1[i]);
        }
    }

    // ---- end-of-sweep fold: tree over 16, then lane^32, then parities ----
    float v0, v1;
    {
        float a0 = min3f(mn0[0],  mn0[1],  mn0[2]);
        float a1 = min3f(mn0[3],  mn0[4],  mn0[5]);
        float a2 = min3f(mn0[6],  mn0[7],  mn0[8]);
        float a3 = min3f(mn0[9],  mn0[10], mn0[11]);
        float a4 = min3f(mn0[12], mn0[13], mn0[14]);
        v0 = min3f(min3f(a0, a1, a2), min3f(a3, a4, mn0[15]),
                   1e30f);
        float b0 = min3f(mn1[0],  mn1[1],  mn1[2]);
        float b1 = min3f(mn1[3],  mn1[4],  mn1[5]);
        float b2 = min3f(mn1[6],  mn1[7],  mn1[8]);
        float b3 = min3f(mn1[9],  mn1[10], mn1[11]);
        float b4 = min3f(mn1[12], mn1[13], mn1[14]);
        v1 = min3f(min3f(b0, b1, b2), min3f(b3, b4, mn1[15]),
                   1e30f);
    }
    v0 = fminf(v0, __shfl_xor(v0, 32));      // rows split across lane halves
    v1 = fminf(v1, __shfl_xor(v1, 32));
    if (lane < 32) {
        comb[h][g * 64 + m]      = v0;
        comb[h][g * 64 + 32 + m] = v1;
    }
    __syncthreads();

    // merge parities, fold |q|^2, sqrt, block-sum (threads 0..255)
    float s = 0.0f;
    if (tid < QPB) {
        float vv = fminf(comb[0][tid], comb[1][tid]);
        float dd = fmaxf(fmaf(0.5f, vv, q2s[tid]), 0.0f);
        s = sqrtf(dd);
    }
    if (wv < 4) {
#pragma unroll
        for (int off = 32; off; off >>= 1) s += __shfl_xor(s, off);
        if (lane == 0) ps[wv] = s;
    }
    __syncthreads();

    if (tid == 0) {
        atomicAdd(accum, ps[0] + ps[1] + ps[2] + ps[3]);
        __threadfence();
        if (atomicAdd(counter, 1u) == NBLK - 1) {   // last block finalizes
            float total = atomicAdd(accum, 0.0f);   // coherent read
            float loss  = total * (1.0f / (float)(B_ * NPTS));
            out[0] = loss;          // WEIGHT * loss, WEIGHT = 1
            out[1] = loss;          // helper_loss
            out[2] = 0.1f * loss;   // helper_cderr = p1 chamfer * xyz_unit
        }
    }
}

// ------------------------------------------------------------------
extern "C" void kernel_launch(void* const* d_in, const int* in_sizes, int n_in,
                              void* d_out, int out_size, void* d_ws, size_t ws_size,
                              hipStream_t stream) {
    const float* pred = (const float*)d_in[0];
    const float* gt   = (const float*)d_in[1];
    float*    out     = (float*)d_out;
    float*    accum   = (float*)d_ws;
    unsigned* counter = (unsigned*)d_ws + 1;

    hipMemsetAsync(d_ws, 0, 8, stream);
    chamfer_mfma<<<dim3(NQC, B_, 2), BLK, 0, stream>>>(pred, gt, accum, counter, out);
}

// Round 11
// 91.909 us; speedup vs baseline: 1.2363x; 1.2363x over previous
//
#include <hip/hip_runtime.h>
#include <hip/hip_fp16.h>

typedef __attribute__((ext_vector_type(8)))  _Float16 half8;
typedef __attribute__((ext_vector_type(16))) float    f32x16;

#define B_   16
#define NPTS 4096                      // points per batch (N == M == 4096)

constexpr int BLK  = 256;              // 4 waves
constexpr int WV   = 4;
constexpr int QPW  = 32;               // queries per wave (one MFMA N-dim)
constexpr int QPB  = WV * QPW;         // 128 queries per block
constexpr int NQC  = NPTS / QPB;       // 32 query chunks
constexpr int RT   = 1024;             // targets staged per round (16 KB LDS)
constexpr int NR   = NPTS / RT;        // 4 rounds
constexpr int TPR  = RT / 32;          // 32 tiles of 32 targets per round
constexpr int NBLK = 2 * B_ * NQC;     // 1024 blocks

__device__ __forceinline__ float min3f(float a, float b, float c) {
    return fminf(fminf(a, b), c);      // -> v_min3_f32
}

// ------------------------------------------------------------------
// Fused MFMA chamfer (R8 wave-shape, pair-tile fold). Each wave owns 32
// queries (one fp16 B-fragment [x,y,z,1,1,0,0,0], dup K-halves) and per
// iteration processes TWO target tiles: 2 broadcast ds_read_b128 -> 2
// independent MFMAs -> fold mn[i] = min3(mn[i], d0[i], d1[i]): 16 min3
// per 2 tiles = 8 VALU insts/tile (minimum possible: each D register
// touched exactly once), in 16 independent dependency chains (no serial
// per-tile tree). Final tree runs once per wave. Numerics identical to
// the verified R7-R10 lineage: A row = [-2x,-2y,-2z,g2hi,g2lo,0,0,0],
// D = 2(|g|^2 - 2 q.g), d^2 = 0.5*minD + |q|^2, same fp16-rounded coords.
__global__ __launch_bounds__(BLK, 4) void chamfer_mfma(
        const float* __restrict__ pred, const float* __restrict__ gt,
        float* __restrict__ accum, unsigned* __restrict__ counter,
        float* __restrict__ out) {
    const int qc  = blockIdx.x;
    const int b   = blockIdx.y;
    const int dir = blockIdx.z;
    const float* qsrc = dir ? gt   : pred;   // queries
    const float* tsrc = dir ? pred : gt;     // targets

    __shared__ uint4 sh[RT];                 // 16 KB staged A-frag rows
    __shared__ float ps[WV];

    const int tid  = threadIdx.x;
    const int lane = tid & 63;
    const int wv   = tid >> 6;
    const int m    = lane & 31;

    // ---- B fragment: this lane's query (col = lane&31 of its wave) ----
    const float* qp = qsrc + (b * NPTS + qc * QPB + wv * QPW + m) * 3;
    __half hqx = __float2half(qp[0]);
    __half hqy = __float2half(qp[1]);
    __half hqz = __float2half(qp[2]);
    float fqx = __half2float(hqx), fqy = __half2float(hqy), fqz = __half2float(hqz);
    const float q2 = fmaf(fqx, fqx, fmaf(fqy, fqy, fqz * fqz));
    uint4 bu;
    bu.x = (unsigned)__half_as_ushort(hqx) | ((unsigned)__half_as_ushort(hqy) << 16);
    bu.y = (unsigned)__half_as_ushort(hqz) | (0x3C00u << 16);   // {z, 1.0}
    bu.z = 0x3C00u;                                             // {1.0, 0}
    bu.w = 0u;
    const half8 bfrag = __builtin_bit_cast(half8, bu);

    f32x16 zero;
#pragma unroll
    for (int i = 0; i < 16; ++i) zero[i] = 0.0f;
    f32x16 mn;
#pragma unroll
    for (int i = 0; i < 16; ++i) mn[i] = 1e30f;

    for (int r = 0; r < NR; ++r) {
        if (r) __syncthreads();
        // ---- stage RT targets as A-frag rows (4 per thread) ----
        const float* tp = tsrc + (b * NPTS + r * RT) * 3;
#pragma unroll
        for (int k = 0; k < RT / BLK; ++k) {
            int j = k * BLK + tid;
            __half hx = __float2half(tp[3 * j + 0]);
            __half hy = __float2half(tp[3 * j + 1]);
            __half hz = __float2half(tp[3 * j + 2]);
            float fx = __half2float(hx), fy = __half2float(hy), fz = __half2float(hz);
            float g2 = fmaf(fx, fx, fmaf(fy, fy, fz * fz));
            __half ax = __float2half(-2.0f * fx);
            __half ay = __float2half(-2.0f * fy);
            __half az = __float2half(-2.0f * fz);
            __half g2hi = __float2half(g2);
            __half g2lo = __float2half(g2 - __half2float(g2hi));
            uint4 w;
            w.x = (unsigned)__half_as_ushort(ax) | ((unsigned)__half_as_ushort(ay) << 16);
            w.y = (unsigned)__half_as_ushort(az) | ((unsigned)__half_as_ushort(g2hi) << 16);
            w.z = (unsigned)__half_as_ushort(g2lo);
            w.w = 0u;
            sh[j] = w;
        }
        __syncthreads();

        // ---- sweep 32 tiles, two per iteration ----
#pragma unroll 4
        for (int t = 0; t < TPR; t += 2) {
            uint4 au0 = sh[t * 32 + m];          // broadcast (lanes L, L+32)
            uint4 au1 = sh[t * 32 + 32 + m];
            half8 a0 = __builtin_bit_cast(half8, au0);
            half8 a1 = __builtin_bit_cast(half8, au1);
            f32x16 d0 = __builtin_amdgcn_mfma_f32_32x32x16_f16(a0, bfrag, zero, 0, 0, 0);
            f32x16 d1 = __builtin_amdgcn_mfma_f32_32x32x16_f16(a1, bfrag, zero, 0, 0, 0);
#pragma unroll
            for (int i = 0; i < 16; ++i)
                mn[i] = min3f(mn[i], d0[i], d1[i]);   // 8 insts/tile, 16 indep chains
        }
    }

    // ---- final fold: tree over 16 regs, then lane^32 row-half merge ----
    float a0 = min3f(mn[0],  mn[1],  mn[2]);
    float a1 = min3f(mn[3],  mn[4],  mn[5]);
    float a2 = min3f(mn[6],  mn[7],  mn[8]);
    float a3 = min3f(mn[9],  mn[10], mn[11]);
    float a4 = min3f(mn[12], mn[13], mn[14]);
    float v  = fminf(min3f(a0, a1, a2), min3f(a3, a4, mn[15]));
    v = fminf(v, __shfl_xor(v, 32));

    float dd = fmaxf(fmaf(0.5f, v, q2), 0.0f);   // undo K-dup, fold |q|^2
    float s  = sqrtf(dd);
#pragma unroll
    for (int off = 32; off; off >>= 1) s += __shfl_xor(s, off);
    if (lane == 0) ps[wv] = 0.5f * s;            // each query counted twice
    __syncthreads();

    if (tid == 0) {
        atomicAdd(accum, ps[0] + ps[1] + ps[2] + ps[3]);
        __threadfence();
        if (atomicAdd(counter, 1u) == NBLK - 1) {   // last block finalizes
            float total = atomicAdd(accum, 0.0f);   // coherent read
            float loss  = total * (1.0f / (float)(B_ * NPTS));
            out[0] = loss;          // WEIGHT * loss, WEIGHT = 1
            out[1] = loss;          // helper_loss
            out[2] = 0.1f * loss;   // helper_cderr = p1 chamfer * xyz_unit
        }
    }
}

// ------------------------------------------------------------------
extern "C" void kernel_launch(void* const* d_in, const int* in_sizes, int n_in,
                              void* d_out, int out_size, void* d_ws, size_t ws_size,
                              hipStream_t stream) {
    const float* pred = (const float*)d_in[0];
    const float* gt   = (const float*)d_in[1];
    float*    out     = (float*)d_out;
    float*    accum   = (float*)d_ws;
    unsigned* counter = (unsigned*)d_ws + 1;

    hipMemsetAsync(d_ws, 0, 8, stream);
    chamfer_mfma<<<dim3(NQC, B_, 2), BLK, 0, stream>>>(pred, gt, accum, counter, out);
}